// Round 6
// baseline (161.600 us; speedup 1.0000x reference)
//
#include <hip/hip_runtime.h>
#include <math.h>

#define BB 4
#define CC 256
#define HWN 4096
#define NTOK 16384                 // BB*HWN
#define SCQ 0.09016844136f         // (1/sqrt(256)) * log2(e)

typedef __attribute__((ext_vector_type(8))) short short8;
typedef __attribute__((ext_vector_type(4))) float f32x4;
typedef unsigned short ushort_t;

__device__ __forceinline__ ushort_t f2bf(float f) {
    unsigned int u = __float_as_uint(f);
    unsigned int r = (u + 0x7FFFu + ((u >> 16) & 1u)) >> 16;   // RNE
    return (ushort_t)r;
}
__device__ __forceinline__ unsigned int pack2(float a, float b) {
    return (unsigned int)f2bf(a) | ((unsigned int)f2bf(b) << 16);
}

// ---------------------------------------------------------------------------
// Fused projection: feature [b][c][tok] fp32 -> Q,K bf16 token-major, MFMA.
// Block = 64 tokens x 64 d, grid 1024 (dtile fastest -> 4 consecutive blocks
// share the same staged feature chunks in L2). Per 64-c chunk: stage fp32 to
// LDS, transpose+convert to bf16 LDS (stride 80 -> <=2-way conflicts), MFMA
// with resident accumulators. Weights converted fp32->bf16 in-register
// (Q weights pre-scaled by (1/sqrt C)*log2e). Also zeroes den/nx/ny.
// ---------------------------------------------------------------------------
__global__ __launch_bounds__(256) void proj_kernel(
    const float* __restrict__ feature,
    const float* __restrict__ q_w, const float* __restrict__ k_w,
    const float* __restrict__ q_bias, const float* __restrict__ k_bias,
    ushort_t* __restrict__ qb, ushort_t* __restrict__ kb,
    float* __restrict__ zbuf)
{
    int gid = blockIdx.x * 256 + threadIdx.x;
    if (gid < 3 * NTOK) zbuf[gid] = 0.f;

    int id = blockIdx.x;
    int dt = id & 3;  id >>= 2;
    int tt = id & 63; id >>= 6;
    int b  = id;

    int t = threadIdx.x, w = t >> 6, lane = t & 63;
    int n16 = lane & 15, quad = lane >> 4;
    int tok0 = tt * 64;
    int d0 = dt * 64 + w * 16;

    __shared__ float    lsA[64][68];   // [c][tok] fp32
    __shared__ ushort_t lsB[64][80];   // [tok][c] bf16, stride 80 (granule 10)

    const float* F = feature + (size_t)(b * CC) * HWN;

    f32x4 accq[4], acck[4];
    #pragma unroll
    for (int i = 0; i < 4; i++) {
        accq[i] = (f32x4){0.f, 0.f, 0.f, 0.f};
        acck[i] = (f32x4){0.f, 0.f, 0.f, 0.f};
    }

    int cl = t >> 2, tg = (t & 3) * 16;
    int tok = t >> 2, c16 = (t & 3) * 16;

    for (int ch = 0; ch < 4; ch++) {
        int c0 = ch * 64;
        const float* src = F + (size_t)(c0 + cl) * HWN + tok0 + tg;
        *(float4*)&lsA[cl][tg]      = *(const float4*)(src);
        *(float4*)&lsA[cl][tg + 4]  = *(const float4*)(src + 4);
        *(float4*)&lsA[cl][tg + 8]  = *(const float4*)(src + 8);
        *(float4*)&lsA[cl][tg + 12] = *(const float4*)(src + 12);
        __syncthreads();
        #pragma unroll
        for (int jj = 0; jj < 8; jj++)
            *(unsigned int*)&lsB[tok][c16 + 2 * jj] =
                pack2(lsA[c16 + 2 * jj][tok], lsA[c16 + 2 * jj + 1][tok]);
        __syncthreads();

        #pragma unroll
        for (int kc = 0; kc < 2; kc++) {
            size_t off = (size_t)(d0 + n16) * CC + c0 + kc * 32 + quad * 8;
            float4 a0 = *(const float4*)&q_w[off];
            float4 a1 = *(const float4*)&q_w[off + 4];
            short8 aq, ak;
            aq[0] = (short)f2bf(a0.x * SCQ); aq[1] = (short)f2bf(a0.y * SCQ);
            aq[2] = (short)f2bf(a0.z * SCQ); aq[3] = (short)f2bf(a0.w * SCQ);
            aq[4] = (short)f2bf(a1.x * SCQ); aq[5] = (short)f2bf(a1.y * SCQ);
            aq[6] = (short)f2bf(a1.z * SCQ); aq[7] = (short)f2bf(a1.w * SCQ);
            a0 = *(const float4*)&k_w[off];
            a1 = *(const float4*)&k_w[off + 4];
            ak[0] = (short)f2bf(a0.x); ak[1] = (short)f2bf(a0.y);
            ak[2] = (short)f2bf(a0.z); ak[3] = (short)f2bf(a0.w);
            ak[4] = (short)f2bf(a1.x); ak[5] = (short)f2bf(a1.y);
            ak[6] = (short)f2bf(a1.z); ak[7] = (short)f2bf(a1.w);
            #pragma unroll
            for (int tokt = 0; tokt < 4; tokt++) {
                short8 bf = *(const short8*)&lsB[tokt * 16 + n16][kc * 32 + quad * 8];
                accq[tokt] = __builtin_amdgcn_mfma_f32_16x16x32_bf16(aq, bf, accq[tokt], 0, 0, 0);
                acck[tokt] = __builtin_amdgcn_mfma_f32_16x16x32_bf16(ak, bf, acck[tokt], 0, 0, 0);
            }
        }
    }

    float bqv[4], bkv[4];
    #pragma unroll
    for (int r = 0; r < 4; r++) {
        bqv[r] = q_bias[d0 + quad * 4 + r] * SCQ;
        bkv[r] = k_bias[d0 + quad * 4 + r];
    }
    #pragma unroll
    for (int tokt = 0; tokt < 4; tokt++) {
        size_t row = (size_t)(b * HWN + tok0 + tokt * 16 + n16) * CC + d0 + quad * 4;
        ushort4 oq, ok;
        oq.x = f2bf(accq[tokt][0] + bqv[0]); oq.y = f2bf(accq[tokt][1] + bqv[1]);
        oq.z = f2bf(accq[tokt][2] + bqv[2]); oq.w = f2bf(accq[tokt][3] + bqv[3]);
        ok.x = f2bf(acck[tokt][0] + bkv[0]); ok.y = f2bf(acck[tokt][1] + bkv[1]);
        ok.z = f2bf(acck[tokt][2] + bkv[2]); ok.w = f2bf(acck[tokt][3] + bkv[3]);
        *(ushort4*)&qb[row] = oq;
        *(ushort4*)&kb[row] = ok;
    }
}

// ---------------------------------------------------------------------------
// Flash MFMA attention. Block = (b, 128-q, 256-key range), 4 waves; grid 2048
// qt-fastest (32 consecutive blocks share a K-range -> L2 reuse).
// 16-key stages, double-buffered 2 x 8 KB XOR-swizzled LDS; 18 KB total ->
// ~6 blocks/CU residency. Q pre-scaled by (1/16)*log2e => p = exp2(acc).
// No-max softmax => key-split additively exact via atomics.
// ---------------------------------------------------------------------------
__global__ __launch_bounds__(256) void attn_kernel(
    const ushort_t* __restrict__ qb, const ushort_t* __restrict__ kb,
    const float* __restrict__ flow,
    float* __restrict__ den_g, float* __restrict__ nx_g, float* __restrict__ ny_g)
{
    int id = blockIdx.x;
    int qt = id & 31; id >>= 5;
    int sr = id & 15; id >>= 4;
    int b = id;

    int t = threadIdx.x;
    int w = t >> 6, lane = t & 63;
    int n16 = lane & 15, quad = lane >> 4;

    int q0 = qt * 128 + w * 32;
    int s_beg = sr * 256;

    const ushort_t* Qb = qb + (size_t)b * HWN * CC;
    const ushort_t* Kb = kb + (size_t)b * HWN * CC;

    __shared__ __align__(16) ushort_t lk[2][4096];   // 2 x 8 KB swizzled K
    __shared__ float lflow[512];                      // 256 vx + 256 vy

    const float* fx = flow + (size_t)b * 2 * HWN;
    const float* fy = fx + HWN;
    lflow[t]       = fx[s_beg + t];
    lflow[256 + t] = fy[s_beg + t];

    short8 qf[2][8];
    #pragma unroll
    for (int tq = 0; tq < 2; tq++)
        #pragma unroll
        for (int c = 0; c < 8; c++)
            qf[tq][c] = *(const short8*)&Qb[(size_t)(q0 + tq * 16 + n16) * CC
                                            + c * 32 + quad * 8];

    // staging source offsets (XOR swizzle on 16B granules), loop-invariant
    int srcoff[2];
    #pragma unroll
    for (int i = 0; i < 2; i++) {
        int G = i * 256 + t;
        int r = G >> 5, j = G & 31;        // 16 rows x 32 granules
        srcoff[i] = (r * 32 + (j ^ r)) * 16;
    }
    int p16[8];
    #pragma unroll
    for (int c = 0; c < 8; c++)
        p16[c] = (((c * 4 + quad) ^ n16) & 31) * 16;

    float den[2][4], nxa[2][4], nya[2][4];
    #pragma unroll
    for (int tq = 0; tq < 2; tq++)
        #pragma unroll
        for (int r = 0; r < 4; r++) { den[tq][r] = 0.f; nxa[tq][r] = 0.f; nya[tq][r] = 0.f; }

    // prologue: stage tile 0 into buffer 0
    {
        const char* gsrc = (const char*)(Kb + (size_t)s_beg * CC);
        char* ldst = (char*)lk[0] + t * 16;
        #pragma unroll
        for (int i = 0; i < 2; i++)
            __builtin_amdgcn_global_load_lds(
                (const __attribute__((address_space(1))) unsigned int*)(gsrc + srcoff[i]),
                (__attribute__((address_space(3))) unsigned int*)(ldst + i * 4096),
                16, 0, 0);
    }

    for (int st = 0; st < 16; st++) {
        __syncthreads();   // buffer st&1 staged; prior reads of other buffer done
        if (st + 1 < 16) {
            const char* gsrc = (const char*)(Kb + (size_t)(s_beg + (st + 1) * 16) * CC);
            char* ldst = (char*)lk[(st + 1) & 1] + t * 16;
            #pragma unroll
            for (int i = 0; i < 2; i++)
                __builtin_amdgcn_global_load_lds(
                    (const __attribute__((address_space(1))) unsigned int*)(gsrc + srcoff[i]),
                    (__attribute__((address_space(3))) unsigned int*)(ldst + i * 4096),
                    16, 0, 0);
        }
        const char* base = (const char*)lk[st & 1];
        int rbase = n16 * 512;

        f32x4 a0 = {0.f, 0.f, 0.f, 0.f};
        f32x4 a1 = {0.f, 0.f, 0.f, 0.f};
        #pragma unroll
        for (int c = 0; c < 8; c++) {
            short8 kf = *(const short8*)(base + rbase + p16[c]);
            a0 = __builtin_amdgcn_mfma_f32_16x16x32_bf16(qf[0][c], kf, a0, 0, 0, 0);
            a1 = __builtin_amdgcn_mfma_f32_16x16x32_bf16(qf[1][c], kf, a1, 0, 0, 0);
        }
        float vx = lflow[st * 16 + n16];
        float vy = lflow[256 + st * 16 + n16];
        #pragma unroll
        for (int r = 0; r < 4; r++) {
            float p0 = exp2f(a0[r]);
            float p1 = exp2f(a1[r]);
            den[0][r] += p0;                      den[1][r] += p1;
            nxa[0][r] = fmaf(p0, vx, nxa[0][r]);  nxa[1][r] = fmaf(p1, vx, nxa[1][r]);
            nya[0][r] = fmaf(p0, vy, nya[0][r]);  nya[1][r] = fmaf(p1, vy, nya[1][r]);
        }
    }

    #pragma unroll
    for (int tq = 0; tq < 2; tq++)
        #pragma unroll
        for (int r = 0; r < 4; r++) {
            #pragma unroll
            for (int off = 8; off >= 1; off >>= 1) {
                den[tq][r] += __shfl_down(den[tq][r], off, 16);
                nxa[tq][r] += __shfl_down(nxa[tq][r], off, 16);
                nya[tq][r] += __shfl_down(nya[tq][r], off, 16);
            }
        }
    if (n16 == 0) {
        #pragma unroll
        for (int tq = 0; tq < 2; tq++)
            #pragma unroll
            for (int r = 0; r < 4; r++) {
                int qrow = q0 + tq * 16 + quad * 4 + r;
                int gi = b * HWN + qrow;
                atomicAdd(&den_g[gi], den[tq][r]);
                atomicAdd(&nx_g[gi],  nxa[tq][r]);
                atomicAdd(&ny_g[gi],  nya[tq][r]);
            }
    }
}

// ---------------------------------------------------------------------------
__global__ __launch_bounds__(256) void finalize_kernel(
    const float* __restrict__ den_g, const float* __restrict__ nx_g,
    const float* __restrict__ ny_g, float* __restrict__ out)
{
    int idx = blockIdx.x * 256 + threadIdx.x;  // b*HW + n
    int b = idx >> 12, n = idx & 4095;
    float inv = 1.0f / den_g[idx];
    out[(size_t)b * 2 * HWN + n]       = nx_g[idx] * inv;
    out[(size_t)b * 2 * HWN + HWN + n] = ny_g[idx] * inv;
}

extern "C" void kernel_launch(void* const* d_in, const int* in_sizes, int n_in,
                              void* d_out, int out_size, void* d_ws, size_t ws_size,
                              hipStream_t stream) {
    const float* feature = (const float*)d_in[0];
    const float* flow    = (const float*)d_in[1];
    const float* q_w     = (const float*)d_in[2];
    const float* q_b     = (const float*)d_in[3];
    const float* k_w     = (const float*)d_in[4];
    const float* k_b     = (const float*)d_in[5];
    float* out = (float*)d_out;

    ushort_t* qbuf = (ushort_t*)d_ws;                     // [NTOK][CC] bf16
    ushort_t* kbuf = qbuf + (size_t)NTOK * CC;            // [NTOK][CC] bf16
    float* den = (float*)(kbuf + (size_t)NTOK * CC);      // [NTOK]
    float* nx  = den + NTOK;
    float* ny  = nx + NTOK;

    proj_kernel<<<1024, 256, 0, stream>>>(feature, q_w, k_w, q_b, k_b,
                                          qbuf, kbuf, den);   // zeroes den/nx/ny
    attn_kernel<<<2048, 256, 0, stream>>>(qbuf, kbuf, flow, den, nx, ny);
    finalize_kernel<<<64, 256, 0, stream>>>(den, nx, ny, out);
}

// Round 7
// 141.192 us; speedup vs baseline: 1.1445x; 1.1445x over previous
//
#include <hip/hip_runtime.h>
#include <math.h>

#define BB 4
#define CC 256
#define HWN 4096
#define NTOK 16384                 // BB*HWN
#define SCQ 0.09016844136f         // (1/sqrt(256)) * log2(e)

typedef __attribute__((ext_vector_type(8))) short short8;
typedef __attribute__((ext_vector_type(4))) float f32x4;
typedef unsigned short ushort_t;

__device__ __forceinline__ ushort_t f2bf(float f) {
    unsigned int u = __float_as_uint(f);
    unsigned int r = (u + 0x7FFFu + ((u >> 16) & 1u)) >> 16;   // RNE
    return (ushort_t)r;
}
__device__ __forceinline__ unsigned int pack2(float a, float b) {
    return (unsigned int)f2bf(a) | ((unsigned int)f2bf(b) << 16);
}

// ---------------------------------------------------------------------------
// Fused projection. Block = 64 tokens (all 256 d), grid 256.
// Phase 1: stage feature [256c x 64tok] fp32 -> bf16 LDS token-major (once;
// feature read exactly once chip-wide). Phase 2 (no barriers): per wave,
// 64 d x 256 c MFMA for Q and K, weights converted fp32->bf16 in-register
// (Q weights and bias pre-scaled by (1/sqrt C)*log2e). Also zeroes den/nx/ny.
// ---------------------------------------------------------------------------
__global__ __launch_bounds__(256, 2) void proj_kernel(
    const float* __restrict__ feature,
    const float* __restrict__ q_w, const float* __restrict__ k_w,
    const float* __restrict__ q_bias, const float* __restrict__ k_bias,
    ushort_t* __restrict__ qb, ushort_t* __restrict__ kb,
    float* __restrict__ zbuf)
{
    int gid = blockIdx.x * 256 + threadIdx.x;
    if (gid < 3 * NTOK) zbuf[gid] = 0.f;

    int tt = blockIdx.x & 63;
    int b  = blockIdx.x >> 6;
    int tok0 = tt * 64;

    int t = threadIdx.x, w = t >> 6, lane = t & 63;
    int n16 = lane & 15, quad = lane >> 4;

    __shared__ float    lsA[64][69];    // [c-in-chunk][tok] fp32, stride 69
    __shared__ ushort_t lsB[64][264];   // [tok][c 0..255] bf16, stride 264

    const float* F = feature + (size_t)(b * CC) * HWN;

    int cl = t >> 2, tg = (t & 3) * 16;
    int tokw = t >> 2, c16 = (t & 3) * 16;

    for (int ch = 0; ch < 4; ch++) {
        const float* src = F + (size_t)(ch * 64 + cl) * HWN + tok0 + tg;
        *(float4*)&lsA[cl][tg]      = *(const float4*)(src);
        *(float4*)&lsA[cl][tg + 4]  = *(const float4*)(src + 4);
        *(float4*)&lsA[cl][tg + 8]  = *(const float4*)(src + 8);
        *(float4*)&lsA[cl][tg + 12] = *(const float4*)(src + 12);
        __syncthreads();
        #pragma unroll
        for (int jj = 0; jj < 8; jj++)
            *(unsigned int*)&lsB[tokw][ch * 64 + c16 + 2 * jj] =
                pack2(lsA[c16 + 2 * jj][tokw], lsA[c16 + 2 * jj + 1][tokw]);
        __syncthreads();
    }

    int dw0 = w * 64;
    #pragma unroll
    for (int dsub = 0; dsub < 4; dsub++) {
        int d0 = dw0 + dsub * 16;
        f32x4 accq[4], acck[4];
        #pragma unroll
        for (int i = 0; i < 4; i++) {
            accq[i] = (f32x4){0.f, 0.f, 0.f, 0.f};
            acck[i] = (f32x4){0.f, 0.f, 0.f, 0.f};
        }
        #pragma unroll
        for (int kc = 0; kc < 8; kc++) {
            size_t off = (size_t)(d0 + n16) * CC + kc * 32 + quad * 8;
            float4 a0 = *(const float4*)&q_w[off];
            float4 a1 = *(const float4*)&q_w[off + 4];
            short8 aq, ak;
            aq[0] = (short)f2bf(a0.x * SCQ); aq[1] = (short)f2bf(a0.y * SCQ);
            aq[2] = (short)f2bf(a0.z * SCQ); aq[3] = (short)f2bf(a0.w * SCQ);
            aq[4] = (short)f2bf(a1.x * SCQ); aq[5] = (short)f2bf(a1.y * SCQ);
            aq[6] = (short)f2bf(a1.z * SCQ); aq[7] = (short)f2bf(a1.w * SCQ);
            a0 = *(const float4*)&k_w[off];
            a1 = *(const float4*)&k_w[off + 4];
            ak[0] = (short)f2bf(a0.x); ak[1] = (short)f2bf(a0.y);
            ak[2] = (short)f2bf(a0.z); ak[3] = (short)f2bf(a0.w);
            ak[4] = (short)f2bf(a1.x); ak[5] = (short)f2bf(a1.y);
            ak[6] = (short)f2bf(a1.z); ak[7] = (short)f2bf(a1.w);
            #pragma unroll
            for (int tokt = 0; tokt < 4; tokt++) {
                short8 bf = *(const short8*)&lsB[tokt * 16 + n16][kc * 32 + quad * 8];
                accq[tokt] = __builtin_amdgcn_mfma_f32_16x16x32_bf16(aq, bf, accq[tokt], 0, 0, 0);
                acck[tokt] = __builtin_amdgcn_mfma_f32_16x16x32_bf16(ak, bf, acck[tokt], 0, 0, 0);
            }
        }
        float bqv[4], bkv[4];
        #pragma unroll
        for (int r = 0; r < 4; r++) {
            bqv[r] = q_bias[d0 + quad * 4 + r] * SCQ;
            bkv[r] = k_bias[d0 + quad * 4 + r];
        }
        #pragma unroll
        for (int tokt = 0; tokt < 4; tokt++) {
            size_t row = (size_t)(b * HWN + tok0 + tokt * 16 + n16) * CC + d0 + quad * 4;
            ushort4 oq, ok;
            oq.x = f2bf(accq[tokt][0] + bqv[0]); oq.y = f2bf(accq[tokt][1] + bqv[1]);
            oq.z = f2bf(accq[tokt][2] + bqv[2]); oq.w = f2bf(accq[tokt][3] + bqv[3]);
            ok.x = f2bf(acck[tokt][0] + bkv[0]); ok.y = f2bf(acck[tokt][1] + bkv[1]);
            ok.z = f2bf(acck[tokt][2] + bkv[2]); ok.w = f2bf(acck[tokt][3] + bkv[3]);
            *(ushort4*)&qb[row] = oq;
            *(ushort4*)&kb[row] = ok;
        }
    }
}

// ---------------------------------------------------------------------------
// Flash MFMA attention. Block = (b, 256-q, 512-key range), 4 waves; each wave
// owns 64 q-rows (4 resident A-tiles -> 64 MFMA per 16 ds_read per stage).
// Grid 512 qt-fastest (16 consecutive blocks share a K-range -> L2 reuse).
// 32-key stages, double-buffered 2 x 16 KB XOR-swizzled LDS.
// Q pre-scaled by (1/16)*log2e => p = exp2(acc). No-max softmax => key-split
// additively exact via atomics.
// ---------------------------------------------------------------------------
__global__ __launch_bounds__(256, 2) void attn_kernel(
    const ushort_t* __restrict__ qb, const ushort_t* __restrict__ kb,
    const float* __restrict__ flow,
    float* __restrict__ den_g, float* __restrict__ nx_g, float* __restrict__ ny_g)
{
    int id = blockIdx.x;
    int qt = id & 15; id >>= 4;
    int sr = id & 7;  id >>= 3;
    int b = id;

    int t = threadIdx.x;
    int w = t >> 6, lane = t & 63;
    int n16 = lane & 15, quad = lane >> 4;

    int q0 = qt * 256 + w * 64;
    int s_beg = sr * 512;

    const ushort_t* Qb = qb + (size_t)b * HWN * CC;
    const ushort_t* Kb = kb + (size_t)b * HWN * CC;

    __shared__ __align__(16) ushort_t lk[2][8192];   // 2 x 16 KB swizzled K
    __shared__ float lflow[1024];                     // 512 vx + 512 vy

    const float* fx = flow + (size_t)b * 2 * HWN;
    const float* fy = fx + HWN;
    lflow[t]        = fx[s_beg + t];
    lflow[t + 256]  = fx[s_beg + t + 256];
    lflow[t + 512]  = fy[s_beg + t];
    lflow[t + 768]  = fy[s_beg + t + 256];

    short8 qf[4][8];
    #pragma unroll
    for (int tq = 0; tq < 4; tq++)
        #pragma unroll
        for (int c = 0; c < 8; c++)
            qf[tq][c] = *(const short8*)&Qb[(size_t)(q0 + tq * 16 + n16) * CC
                                            + c * 32 + quad * 8];

    // staging source offsets (XOR swizzle on 16B granules), loop-invariant
    int srcoff[4];
    #pragma unroll
    for (int i = 0; i < 4; i++) {
        int G = i * 256 + t;
        int r = G >> 5, j = G & 31;        // 32 rows x 32 granules
        srcoff[i] = (r * 32 + (j ^ r)) * 16;
    }
    int p16[8];
    #pragma unroll
    for (int c = 0; c < 8; c++)
        p16[c] = (((c * 4 + quad) ^ n16) & 31) * 16;

    float den[4][4], nxa[4][4], nya[4][4];
    #pragma unroll
    for (int tq = 0; tq < 4; tq++)
        #pragma unroll
        for (int r = 0; r < 4; r++) { den[tq][r] = 0.f; nxa[tq][r] = 0.f; nya[tq][r] = 0.f; }

    // prologue: stage tile 0 into buffer 0
    {
        const char* gsrc = (const char*)(Kb + (size_t)s_beg * CC);
        char* ldst = (char*)lk[0] + t * 16;
        #pragma unroll
        for (int i = 0; i < 4; i++)
            __builtin_amdgcn_global_load_lds(
                (const __attribute__((address_space(1))) unsigned int*)(gsrc + srcoff[i]),
                (__attribute__((address_space(3))) unsigned int*)(ldst + i * 4096),
                16, 0, 0);
    }

    for (int st = 0; st < 16; st++) {
        __syncthreads();   // buffer st&1 staged; prior reads of other buffer done
        if (st + 1 < 16) {
            const char* gsrc = (const char*)(Kb + (size_t)(s_beg + (st + 1) * 32) * CC);
            char* ldst = (char*)lk[(st + 1) & 1] + t * 16;
            #pragma unroll
            for (int i = 0; i < 4; i++)
                __builtin_amdgcn_global_load_lds(
                    (const __attribute__((address_space(1))) unsigned int*)(gsrc + srcoff[i]),
                    (__attribute__((address_space(3))) unsigned int*)(ldst + i * 4096),
                    16, 0, 0);
        }
        const char* base = (const char*)lk[st & 1];

        #pragma unroll
        for (int bt = 0; bt < 2; bt++) {
            int rbase = (bt * 16 + n16) * 512;
            int x16   = bt ? 256 : 0;
            f32x4 a0 = {0.f, 0.f, 0.f, 0.f};
            f32x4 a1 = {0.f, 0.f, 0.f, 0.f};
            f32x4 a2 = {0.f, 0.f, 0.f, 0.f};
            f32x4 a3 = {0.f, 0.f, 0.f, 0.f};
            #pragma unroll
            for (int c = 0; c < 8; c++) {
                short8 kf = *(const short8*)(base + rbase + (p16[c] ^ x16));
                a0 = __builtin_amdgcn_mfma_f32_16x16x32_bf16(qf[0][c], kf, a0, 0, 0, 0);
                a1 = __builtin_amdgcn_mfma_f32_16x16x32_bf16(qf[1][c], kf, a1, 0, 0, 0);
                a2 = __builtin_amdgcn_mfma_f32_16x16x32_bf16(qf[2][c], kf, a2, 0, 0, 0);
                a3 = __builtin_amdgcn_mfma_f32_16x16x32_bf16(qf[3][c], kf, a3, 0, 0, 0);
            }
            int sidx = st * 32 + bt * 16 + n16;
            float vx = lflow[sidx];
            float vy = lflow[512 + sidx];
            #pragma unroll
            for (int r = 0; r < 4; r++) {
                float p0 = exp2f(a0[r]);
                float p1 = exp2f(a1[r]);
                float p2 = exp2f(a2[r]);
                float p3 = exp2f(a3[r]);
                den[0][r] += p0; den[1][r] += p1; den[2][r] += p2; den[3][r] += p3;
                nxa[0][r] = fmaf(p0, vx, nxa[0][r]); nxa[1][r] = fmaf(p1, vx, nxa[1][r]);
                nxa[2][r] = fmaf(p2, vx, nxa[2][r]); nxa[3][r] = fmaf(p3, vx, nxa[3][r]);
                nya[0][r] = fmaf(p0, vy, nya[0][r]); nya[1][r] = fmaf(p1, vy, nya[1][r]);
                nya[2][r] = fmaf(p2, vy, nya[2][r]); nya[3][r] = fmaf(p3, vy, nya[3][r]);
            }
        }
    }

    #pragma unroll
    for (int tq = 0; tq < 4; tq++)
        #pragma unroll
        for (int r = 0; r < 4; r++) {
            #pragma unroll
            for (int off = 8; off >= 1; off >>= 1) {
                den[tq][r] += __shfl_down(den[tq][r], off, 16);
                nxa[tq][r] += __shfl_down(nxa[tq][r], off, 16);
                nya[tq][r] += __shfl_down(nya[tq][r], off, 16);
            }
        }
    if (n16 == 0) {
        #pragma unroll
        for (int tq = 0; tq < 4; tq++)
            #pragma unroll
            for (int r = 0; r < 4; r++) {
                int qrow = q0 + tq * 16 + quad * 4 + r;
                int gi = b * HWN + qrow;
                atomicAdd(&den_g[gi], den[tq][r]);
                atomicAdd(&nx_g[gi],  nxa[tq][r]);
                atomicAdd(&ny_g[gi],  nya[tq][r]);
            }
    }
}

// ---------------------------------------------------------------------------
__global__ __launch_bounds__(256) void finalize_kernel(
    const float* __restrict__ den_g, const float* __restrict__ nx_g,
    const float* __restrict__ ny_g, float* __restrict__ out)
{
    int idx = blockIdx.x * 256 + threadIdx.x;  // b*HW + n
    int b = idx >> 12, n = idx & 4095;
    float inv = 1.0f / den_g[idx];
    out[(size_t)b * 2 * HWN + n]       = nx_g[idx] * inv;
    out[(size_t)b * 2 * HWN + HWN + n] = ny_g[idx] * inv;
}

extern "C" void kernel_launch(void* const* d_in, const int* in_sizes, int n_in,
                              void* d_out, int out_size, void* d_ws, size_t ws_size,
                              hipStream_t stream) {
    const float* feature = (const float*)d_in[0];
    const float* flow    = (const float*)d_in[1];
    const float* q_w     = (const float*)d_in[2];
    const float* q_b     = (const float*)d_in[3];
    const float* k_w     = (const float*)d_in[4];
    const float* k_b     = (const float*)d_in[5];
    float* out = (float*)d_out;

    ushort_t* qbuf = (ushort_t*)d_ws;                     // [NTOK][CC] bf16
    ushort_t* kbuf = qbuf + (size_t)NTOK * CC;            // [NTOK][CC] bf16
    float* den = (float*)(kbuf + (size_t)NTOK * CC);      // [NTOK]
    float* nx  = den + NTOK;
    float* ny  = nx + NTOK;

    proj_kernel<<<256, 256, 0, stream>>>(feature, q_w, k_w, q_b, k_b,
                                         qbuf, kbuf, den);   // zeroes den/nx/ny
    attn_kernel<<<512, 256, 0, stream>>>(qbuf, kbuf, flow, den, nx, ny);
    finalize_kernel<<<64, 256, 0, stream>>>(den, nx, ny, out);
}